// Round 7
// baseline (713.762 us; speedup 1.0000x reference)
//
#include <hip/hip_runtime.h>
#include <math.h>

namespace {

constexpr int B_ = 64;
constexpr int C_ = 192;
constexpr int H_ = 56;
constexpr int W_ = 56;
constexpr int HW_ = H_ * W_;          // 3136
constexpr int CHW_ = C_ * HW_;        // 602112
constexpr float PI_F = 3.14159265358979323846f;

typedef __attribute__((ext_vector_type(8))) short short8;
typedef __attribute__((ext_vector_type(4))) short short4v;
typedef __attribute__((ext_vector_type(4))) float f32x4;

__device__ inline unsigned short f2bf(float f) {
  union { float f; unsigned u; } v{f};
  unsigned r = v.u + 0x7FFFu + ((v.u >> 16) & 1u);
  return (unsigned short)(r >> 16);
}

// XOR swizzle for [row][c] bf16 tiles, row stride 200 elems (16B granular)
__device__ inline int swz(int row) { return ((row >> 1) & 7) << 3; }

// ---------------------------------------------------------------------------
// K0: DCT-II basis table
// ---------------------------------------------------------------------------
__global__ void k_tables(float* __restrict__ cos_tab) {
  int i = blockIdx.x * 256 + threadIdx.x;
  if (i >= HW_) return;
  int n = i / W_;
  int x = i - n * W_;
  float wx = ((float)x + 0.5f) / 56.0f;
  float v = cosf(((float)n * wx) * PI_F) * 0.18898223650461362f;
  if (n == 0) v *= 0.7071067811865476f;
  cos_tab[i] = v;
}

// ---------------------------------------------------------------------------
// K_wexp: wexp[c][hw] = exp(-relu(fe@tok_w+tok_b) * (n^2+m^2))
// ---------------------------------------------------------------------------
__global__ __launch_bounds__(192) void k_wexp(const float* __restrict__ fe,
                                              const float* __restrict__ tkw,
                                              const float* __restrict__ tkb,
                                              float* __restrict__ wexp) {
  __shared__ float sfe[16][C_];
  int hw0 = blockIdx.x * 16;
  int t = threadIdx.x;
  for (int p = 0; p < 16; ++p) sfe[p][t] = fe[(size_t)(hw0 + p) * C_ + t];
  __syncthreads();
  float acc[16];
#pragma unroll
  for (int p = 0; p < 16; ++p) acc[p] = 0.f;
  for (int i = 0; i < C_; ++i) {
    float wv = tkw[i * C_ + t];
#pragma unroll
    for (int p = 0; p < 16; ++p) acc[p] = fmaf(sfe[p][i], wv, acc[p]);
  }
  float bias = tkb[t];
  const float step = PI_F / 56.0f;
#pragma unroll
  for (int p = 0; p < 16; ++p) {
    int hw = hw0 + p;
    int hh = hw / W_;
    int ww = hw - hh * W_;
    float nh = step * (float)hh;
    float nm = step * (float)ww;
    float a = nh * nh + nm * nm;
    float k = fmaxf(acc[p] + bias, 0.0f);
    wexp[(size_t)t * HW_ + hw] = expf(-k * a);
  }
}

// ---------------------------------------------------------------------------
// K_prep_w: lwT[j][c] = bf16(lin_w[c][j]), owT[j][c] = bf16(out_w[c][j])
// ---------------------------------------------------------------------------
__global__ __launch_bounds__(256) void k_prep_w(const float* __restrict__ lw,
                                                const float* __restrict__ ow,
                                                unsigned short* __restrict__ lwT,
                                                unsigned short* __restrict__ owT) {
  int i = blockIdx.x * 256 + threadIdx.x;
  if (i < 384 * 192) {
    int j = i / 192, c = i - j * 192;
    lwT[i] = f2bf(lw[c * 384 + j]);
  } else if (i < 384 * 192 + 192 * 192) {
    int k = i - 384 * 192;
    int j = k / 192, c = k - j * 192;
    owT[k] = f2bf(ow[c * 192 + j]);
  }
}

// ---------------------------------------------------------------------------
// K1: fused depthwise 3x3 conv + bias + transpose-to-bf16 (v3).
// 512 thr, wave cr owns c in [24cr,24cr+24). Loads batched 72-wide:
// float tv[8][9] staging -> all 8 channels' 9 taps issue before first wait
// (fixes R6's VGPR=44 serial schedule; latency hiding scales with
// loads-in-flight).
// ---------------------------------------------------------------------------
__global__ __launch_bounds__(512) void k_convt(const float* __restrict__ x,
                                               const float* __restrict__ dww,
                                               const float* __restrict__ dwb,
                                               unsigned short* __restrict__ yT) {
  __shared__ unsigned short t[64 * 200];
  int b = blockIdx.y, pt = blockIdx.x;
  int tid = threadIdx.x;
  int p = tid & 63, cr = tid >> 6;
  int pos = pt * 64 + p;
  int h = pos / 56, w = pos - h * 56;
  bool hn = h > 0, hp = h < 55, wn = w > 0, wq = w < 55;
  int o00 = (hn && wn) ? -57 : 0, o01 = hn ? -56 : 0, o02 = (hn && wq) ? -55 : 0;
  int o10 = wn ? -1 : 0, o12 = wq ? 1 : 0;
  int o20 = (hp && wn) ? 55 : 0, o21 = hp ? 56 : 0, o22 = (hp && wq) ? 57 : 0;
  float f00 = (hn && wn) ? 1.f : 0.f, f01 = hn ? 1.f : 0.f, f02 = (hn && wq) ? 1.f : 0.f;
  float f10 = wn ? 1.f : 0.f, f12 = wq ? 1.f : 0.f;
  float f20 = (hp && wn) ? 1.f : 0.f, f21 = hp ? 1.f : 0.f, f22 = (hp && wq) ? 1.f : 0.f;
  const float* xb = x + (size_t)b * CHW_ + pos;
#pragma unroll
  for (int q = 0; q < 3; ++q) {
    float tv[8][9];
#pragma unroll
    for (int e = 0; e < 8; ++e) {
      const float* xc = xb + (size_t)(cr * 24 + q * 8 + e) * HW_;
      tv[e][0] = xc[o00]; tv[e][1] = xc[o01]; tv[e][2] = xc[o02];
      tv[e][3] = xc[o10]; tv[e][4] = xc[0];   tv[e][5] = xc[o12];
      tv[e][6] = xc[o20]; tv[e][7] = xc[o21]; tv[e][8] = xc[o22];
    }
    short8 vv;
#pragma unroll
    for (int e = 0; e < 8; ++e) {
      int c = cr * 24 + q * 8 + e;
      const float* w9 = dww + c * 9;
      float a = dwb[c];
      a = fmaf(tv[e][0] * f00, w9[0], a);
      a = fmaf(tv[e][1] * f01, w9[1], a);
      a = fmaf(tv[e][2] * f02, w9[2], a);
      a = fmaf(tv[e][3] * f10, w9[3], a);
      a = fmaf(tv[e][4], w9[4], a);
      a = fmaf(tv[e][5] * f12, w9[5], a);
      a = fmaf(tv[e][6] * f20, w9[6], a);
      a = fmaf(tv[e][7] * f21, w9[7], a);
      a = fmaf(tv[e][8] * f22, w9[8], a);
      vv[e] = (short)f2bf(a);
    }
    *(short8*)&t[p * 200 + ((cr * 24 + q * 8) ^ swz(p))] = vv;
  }
  __syncthreads();
  unsigned short* o = yT + ((size_t)b * HW_ + pt * 64) * C_;
#pragma unroll
  for (int q = 0; q < 3; ++q) {
    int idx = q * 512 + tid;
    int pp = idx / 24, cb = idx - pp * 24;
    short8 v = *(const short8*)&t[pp * 200 + ((cb * 8) ^ swz(pp))];
    *(short8*)&o[(size_t)idx * 8] = v;
  }
}

// ---------------------------------------------------------------------------
// K2: GEMM1 via MFMA bf16.
// ---------------------------------------------------------------------------
__global__ __launch_bounds__(256) void k_gemm1(const unsigned short* __restrict__ yT,
                                               const unsigned short* __restrict__ lwT,
                                               const float* __restrict__ lb,
                                               float* __restrict__ xp,
                                               float* __restrict__ zb) {
  constexpr int LD = 40;
  __shared__ unsigned short sA[128 * LD];
  __shared__ unsigned short sY[128 * LD];
  int b = blockIdx.y;
  int bx = blockIdx.x;
  int xcd = bx & 7, o8 = bx >> 3;
  int lg = (xcd < 3 ? xcd * 10 : 30 + (xcd - 3) * 9) + o8;
  int pt = lg / 3, jt = lg % 3;
  int pos0 = pt * 128, j0 = jt * 128;
  int tid = threadIdx.x, lane = tid & 63, wv = tid >> 6;
  int wm = wv & 1, wn = wv >> 1;

  int row0 = tid >> 2, row1 = 64 + (tid >> 2), cb = (tid & 3) * 8;
  const unsigned short* a0 = lwT + (size_t)(j0 + row0) * C_ + cb;
  const unsigned short* a1 = lwT + (size_t)(j0 + row1) * C_ + cb;
  int pr0 = pos0 + row0; if (pr0 > HW_ - 1) pr0 = HW_ - 1;
  int pr1 = pos0 + row1; if (pr1 > HW_ - 1) pr1 = HW_ - 1;
  const unsigned short* b0 = yT + ((size_t)b * HW_ + pr0) * C_ + cb;
  const unsigned short* b1 = yT + ((size_t)b * HW_ + pr1) * C_ + cb;
  int d0 = row0 * LD + cb, d1 = row1 * LD + cb;

  f32x4 acc[4][4] = {};
  for (int kk = 0; kk < C_; kk += 32) {
    short8 va0 = *(const short8*)(a0 + kk);
    short8 va1 = *(const short8*)(a1 + kk);
    short8 vb0 = *(const short8*)(b0 + kk);
    short8 vb1 = *(const short8*)(b1 + kk);
    if (kk) __syncthreads();
    *(short8*)&sA[d0] = va0;
    *(short8*)&sA[d1] = va1;
    *(short8*)&sY[d0] = vb0;
    *(short8*)&sY[d1] = vb1;
    __syncthreads();
    int ra = (wm * 64 + (lane & 15)) * LD + (lane >> 4) * 8;
    int rb = (wn * 64 + (lane & 15)) * LD + (lane >> 4) * 8;
    short8 af[4], bf[4];
#pragma unroll
    for (int m = 0; m < 4; ++m) af[m] = *(const short8*)&sA[ra + m * 16 * LD];
#pragma unroll
    for (int n = 0; n < 4; ++n) bf[n] = *(const short8*)&sY[rb + n * 16 * LD];
#pragma unroll
    for (int m = 0; m < 4; ++m)
#pragma unroll
      for (int n = 0; n < 4; ++n)
        acc[m][n] = __builtin_amdgcn_mfma_f32_16x16x32_bf16(af[m], bf[n], acc[m][n], 0, 0, 0);
  }

#pragma unroll
  for (int m = 0; m < 4; ++m) {
    int jb = j0 + wm * 64 + m * 16 + (lane >> 4) * 4;
#pragma unroll
    for (int r = 0; r < 4; ++r) {
      int jg = jb + r;
      float bias = lb[jg];
      float* base = (jg < C_) ? (xp + ((size_t)b * C_ + jg) * HW_)
                              : (zb + ((size_t)b * C_ + (jg - C_)) * HW_);
#pragma unroll
      for (int n = 0; n < 4; ++n) {
        int pos = pos0 + wn * 64 + n * 16 + (lane & 15);
        if (pos < HW_) base[pos] = acc[m][n][r] + bias;
      }
    }
  }
}

// ---------------------------------------------------------------------------
// K4 (v2): spectral sandwich via bf16 MFMA, per (b,c) plane, in-place d_out.
// ---------------------------------------------------------------------------
__global__ __launch_bounds__(256) void k_spec(const float* xp,
                                              const float* __restrict__ cos_tab,
                                              const float* __restrict__ wexp,
                                              float* sout) {
  constexpr int LDT = 72;
  __shared__ unsigned short lds[4 * 64 * LDT];
  __shared__ float sW[56 * 57];
  unsigned short* sCn = lds;                 // [n][h] = cos[n][h]
  unsigned short* sCt = lds + 64 * LDT;      // [h][n] = cos[n][h]
  unsigned short* sP  = lds + 2 * 64 * LDT;  // [w][h] = P[h][w]
  unsigned short* sT  = lds + 3 * 64 * LDT;  // intermediate
  const int tid = threadIdx.x;
  const int bc = blockIdx.x;
  const int c = bc % C_;

  {  // zero pad regions (whole bf16 area)
    uint2* z = (uint2*)lds;
    for (int i = tid; i < 4608; i += 256) z[i] = make_uint2(0u, 0u);
  }
  __syncthreads();

  const float* Pp = xp + (size_t)bc * HW_;
  const float* Wp = wexp + (size_t)c * HW_;
  for (int e = tid; e < HW_; e += 256) {
    int n = e / 56, m = e - n * 56;
    unsigned short cv = f2bf(cos_tab[e]);
    sCn[n * LDT + m] = cv;
    sCt[m * LDT + n] = cv;
    sP[m * LDT + n] = f2bf(Pp[e]);
    sW[n * 57 + m] = Wp[e];
  }
  __syncthreads();

  const int lane = tid & 63, wv = tid >> 6;
  const int wm = wv & 1, wn = wv >> 1;
  const int lr = lane & 15, lk = lane >> 4;
  const int rt0 = wm * 2, ct0 = wn * 2;
  short8 af[2][2], bg[2][2];
  f32x4 acc[2][2];

#define LOADFRAGS(Ab, Bb)                                                        \
  {                                                                              \
    _Pragma("unroll") for (int i = 0; i < 2; ++i) {                              \
      _Pragma("unroll") for (int k = 0; k < 2; ++k) {                            \
        af[i][k] = *(const short8*)&Ab[((rt0 + i) * 16 + lr) * LDT + k * 32 + lk * 8]; \
        bg[i][k] = *(const short8*)&Bb[((ct0 + i) * 16 + lr) * LDT + k * 32 + lk * 8]; \
      }                                                                          \
    }                                                                            \
  }
#define DOMFMA()                                                                 \
  {                                                                              \
    _Pragma("unroll") for (int i = 0; i < 2; ++i) {                              \
      _Pragma("unroll") for (int j = 0; j < 2; ++j) {                            \
        acc[i][j] = {};                                                          \
        acc[i][j] = __builtin_amdgcn_mfma_f32_16x16x32_bf16(af[i][0], bg[j][0], acc[i][j], 0, 0, 0); \
        acc[i][j] = __builtin_amdgcn_mfma_f32_16x16x32_bf16(af[i][1], bg[j][1], acc[i][j], 0, 0, 0); \
      }                                                                          \
    }                                                                            \
  }

  // stage 1: D1[n][w] = sum_h Cn[n][h] * P^T[w][h]  -> sT[n][w]
  LOADFRAGS(sCn, sP);
  __syncthreads();
  DOMFMA();
#pragma unroll
  for (int i = 0; i < 2; ++i)
#pragma unroll
    for (int j = 0; j < 2; ++j)
#pragma unroll
      for (int r = 0; r < 4; ++r)
        sT[((rt0 + i) * 16 + lk * 4 + r) * LDT + (ct0 + j) * 16 + lr] = f2bf(acc[i][j][r]);
  __syncthreads();

  // stage 2: D2[n][m] = sum_w T1[n][w] * Cm[m][w]; gate by W; store sT[m][n]
  LOADFRAGS(sT, sCn);
  __syncthreads();
  DOMFMA();
#pragma unroll
  for (int i = 0; i < 2; ++i)
#pragma unroll
    for (int j = 0; j < 2; ++j) {
      int n0 = (rt0 + i) * 16 + lk * 4;
      int m = (ct0 + j) * 16 + lr;
      int mc = m < 56 ? m : 55;
      short4v pk;
#pragma unroll
      for (int r = 0; r < 4; ++r) {
        int n = n0 + r;
        int nc = n < 56 ? n : 55;
        pk[r] = (short)f2bf(acc[i][j][r] * sW[nc * 57 + mc]);
      }
      *(short4v*)&sT[m * LDT + n0] = pk;
    }
  __syncthreads();

  // stage 3: D3[h][m] = sum_n CnT[h][n] * T2T[m][n]  -> sT[h][m]
  LOADFRAGS(sCt, sT);
  __syncthreads();
  DOMFMA();
#pragma unroll
  for (int i = 0; i < 2; ++i)
#pragma unroll
    for (int j = 0; j < 2; ++j)
#pragma unroll
      for (int r = 0; r < 4; ++r)
        sT[((rt0 + i) * 16 + lk * 4 + r) * LDT + (ct0 + j) * 16 + lr] = f2bf(acc[i][j][r]);
  __syncthreads();

  // stage 4: D4[h][w] = sum_m T3[h][m] * CmT[w][m]  -> global S[h][w]
  LOADFRAGS(sT, sCt);
  DOMFMA();
  float* So = sout + (size_t)bc * HW_;
#pragma unroll
  for (int i = 0; i < 2; ++i)
#pragma unroll
    for (int j = 0; j < 2; ++j) {
      int w = (ct0 + j) * 16 + lr;
      if (w < 56) {
#pragma unroll
        for (int r = 0; r < 4; ++r) {
          int h = (rt0 + i) * 16 + lk * 4 + r;
          if (h < 56) So[h * 56 + w] = acc[i][j][r];
        }
      }
    }
#undef LOADFRAGS
#undef DOMFMA
}

// ---------------------------------------------------------------------------
// K5: LayerNorm -> silu-gate -> GEMM2 via MFMA bf16.
// ---------------------------------------------------------------------------
__global__ __launch_bounds__(256) void k_ln2(const float* s,
                                             const float* __restrict__ z,
                                             const float* __restrict__ gamma,
                                             const float* __restrict__ beta,
                                             const unsigned short* __restrict__ owT,
                                             const float* __restrict__ ob,
                                             float* out) {
  __shared__ unsigned short act[64 * 200];
  __shared__ float red[8][64];
  __shared__ float smu[64], srs[64];
  int b = blockIdx.y, pt = blockIdx.x;
  int tid = threadIdx.x, lane = tid & 63, wv = tid >> 6;
  int p = lane, cr = wv;
  const float* sp = s + (size_t)b * CHW_ + (size_t)(48 * cr) * HW_ + pt * 64 + p;
  const float* zp = z + (size_t)b * CHW_ + (size_t)(48 * cr) * HW_ + pt * 64 + p;
  float sv[48];
  float sum = 0.f, sq = 0.f;
#pragma unroll
  for (int i = 0; i < 48; ++i) {
    float v = sp[(size_t)i * HW_];
    sv[i] = v;
    sum += v;
    sq = fmaf(v, v, sq);
  }
  red[cr][p] = sum;
  red[4 + cr][p] = sq;
  __syncthreads();
  if (tid < 64) {
    float s1 = red[0][tid] + red[1][tid] + red[2][tid] + red[3][tid];
    float s2 = red[4][tid] + red[5][tid] + red[6][tid] + red[7][tid];
    float mu = s1 * (1.0f / 192.0f);
    float var = s2 * (1.0f / 192.0f) - mu * mu;
    smu[tid] = mu;
    srs[tid] = rsqrtf(var + 1e-5f);
  }
  __syncthreads();
  float mu = smu[p], rs = srs[p];
#pragma unroll
  for (int q = 0; q < 6; ++q) {
    short8 vv;
#pragma unroll
    for (int e = 0; e < 8; ++e) {
      int i = 8 * q + e;
      int c = 48 * cr + i;
      float v = (sv[i] - mu) * rs * gamma[c] + beta[c];
      float zz = zp[(size_t)i * HW_];
      v *= zz / (1.0f + expf(-zz));
      vv[e] = (short)f2bf(v);
    }
    *(short8*)&act[p * 200 + ((48 * cr + 8 * q) ^ swz(p))] = vv;
  }
  __syncthreads();

  f32x4 acc[3][4] = {};
  const unsigned short* ap = owT + (size_t)(wv * 48 + (lane & 15)) * C_ + (lane >> 4) * 8;
#pragma unroll
  for (int kk = 0; kk < C_; kk += 32) {
    short8 af[3], bf[4];
#pragma unroll
    for (int m = 0; m < 3; ++m) af[m] = *(const short8*)(ap + m * 16 * C_ + kk);
#pragma unroll
    for (int n = 0; n < 4; ++n) {
      int row = (lane & 15) + 16 * n;
      int co = (kk + (lane >> 4) * 8) ^ swz(row);
      bf[n] = *(const short8*)&act[row * 200 + co];
    }
#pragma unroll
    for (int m = 0; m < 3; ++m)
#pragma unroll
      for (int n = 0; n < 4; ++n)
        acc[m][n] = __builtin_amdgcn_mfma_f32_16x16x32_bf16(af[m], bf[n], acc[m][n], 0, 0, 0);
  }

  float* op = out + (size_t)b * CHW_ + pt * 64;
#pragma unroll
  for (int m = 0; m < 3; ++m) {
    int jb = wv * 48 + m * 16 + (lane >> 4) * 4;
#pragma unroll
    for (int r = 0; r < 4; ++r) {
      int j = jb + r;
      float bias = ob[j];
#pragma unroll
      for (int n = 0; n < 4; ++n) {
        int pos = n * 16 + (lane & 15);
        op[(size_t)j * HW_ + pos] = acc[m][n][r] + bias;
      }
    }
  }
}

}  // namespace

extern "C" void kernel_launch(void* const* d_in, const int* in_sizes, int n_in,
                              void* d_out, int out_size, void* d_ws, size_t ws_size,
                              hipStream_t stream) {
  const float* x = (const float*)d_in[0];
  const float* dww = (const float*)d_in[1];
  const float* dwb = (const float*)d_in[2];
  const float* lw = (const float*)d_in[3];
  const float* lb = (const float*)d_in[4];
  const float* tkw = (const float*)d_in[5];
  const float* tkb = (const float*)d_in[6];
  const float* fe = (const float*)d_in[7];
  const float* gamma = (const float*)d_in[8];
  const float* beta = (const float*)d_in[9];
  const float* ow = (const float*)d_in[10];
  const float* obias = (const float*)d_in[11];
  float* out = (float*)d_out;

  float* ws = (float*)d_ws;
  float* cos_tab = ws;                                  // 3136 f
  float* wexp = cos_tab + HW_;                          // 602112 f
  float* zb = wexp + CHW_;                              // 38535168 f
  unsigned short* lwT = (unsigned short*)(zb + (size_t)B_ * CHW_);  // 73728 u16
  unsigned short* owT = lwT + 384 * C_;                 // 36864 u16
  unsigned short* yT = owT + C_ * C_;                   // 38535168 u16

  hipLaunchKernelGGL(k_tables, dim3(13), dim3(256), 0, stream, cos_tab);
  hipLaunchKernelGGL(k_wexp, dim3(HW_ / 16), dim3(192), 0, stream, fe, tkw, tkb, wexp);
  hipLaunchKernelGGL(k_prep_w, dim3(432), dim3(256), 0, stream, lw, ow, lwT, owT);
  hipLaunchKernelGGL(k_convt, dim3(HW_ / 64, B_), dim3(512), 0, stream, x, dww, dwb, yT);
  hipLaunchKernelGGL(k_gemm1, dim3(75, B_), dim3(256), 0, stream, yT, lwT, lb, out, zb);
  hipLaunchKernelGGL(k_spec, dim3(B_ * C_), dim3(256), 0, stream, out, cos_tab, wexp, out);
  hipLaunchKernelGGL(k_ln2, dim3(HW_ / 64, B_), dim3(256), 0, stream, out, zb, gamma, beta,
                     owT, obias, out);
}

// Round 8
// 547.431 us; speedup vs baseline: 1.3038x; 1.3038x over previous
//
#include <hip/hip_runtime.h>
#include <math.h>

namespace {

constexpr int B_ = 64;
constexpr int C_ = 192;
constexpr int H_ = 56;
constexpr int W_ = 56;
constexpr int HW_ = H_ * W_;          // 3136
constexpr int CHW_ = C_ * HW_;        // 602112
constexpr float PI_F = 3.14159265358979323846f;

typedef __attribute__((ext_vector_type(8))) short short8;
typedef __attribute__((ext_vector_type(4))) short short4v;
typedef __attribute__((ext_vector_type(4))) float f32x4;

__device__ inline unsigned short f2bf(float f) {
  union { float f; unsigned u; } v{f};
  unsigned r = v.u + 0x7FFFu + ((v.u >> 16) & 1u);
  return (unsigned short)(r >> 16);
}

// XOR swizzle for [row][c] bf16 tiles, row stride 200 elems (16B granular)
__device__ inline int swz(int row) { return ((row >> 1) & 7) << 3; }

// ---------------------------------------------------------------------------
// K0: DCT-II basis table
// ---------------------------------------------------------------------------
__global__ void k_tables(float* __restrict__ cos_tab) {
  int i = blockIdx.x * 256 + threadIdx.x;
  if (i >= HW_) return;
  int n = i / W_;
  int x = i - n * W_;
  float wx = ((float)x + 0.5f) / 56.0f;
  float v = cosf(((float)n * wx) * PI_F) * 0.18898223650461362f;
  if (n == 0) v *= 0.7071067811865476f;
  cos_tab[i] = v;
}

// ---------------------------------------------------------------------------
// K_wexp: wexp[c][hw] = exp(-relu(fe@tok_w+tok_b) * (n^2+m^2))
// ---------------------------------------------------------------------------
__global__ __launch_bounds__(192) void k_wexp(const float* __restrict__ fe,
                                              const float* __restrict__ tkw,
                                              const float* __restrict__ tkb,
                                              float* __restrict__ wexp) {
  __shared__ float sfe[16][C_];
  int hw0 = blockIdx.x * 16;
  int t = threadIdx.x;
  for (int p = 0; p < 16; ++p) sfe[p][t] = fe[(size_t)(hw0 + p) * C_ + t];
  __syncthreads();
  float acc[16];
#pragma unroll
  for (int p = 0; p < 16; ++p) acc[p] = 0.f;
  for (int i = 0; i < C_; ++i) {
    float wv = tkw[i * C_ + t];
#pragma unroll
    for (int p = 0; p < 16; ++p) acc[p] = fmaf(sfe[p][i], wv, acc[p]);
  }
  float bias = tkb[t];
  const float step = PI_F / 56.0f;
#pragma unroll
  for (int p = 0; p < 16; ++p) {
    int hw = hw0 + p;
    int hh = hw / W_;
    int ww = hw - hh * W_;
    float nh = step * (float)hh;
    float nm = step * (float)ww;
    float a = nh * nh + nm * nm;
    float k = fmaxf(acc[p] + bias, 0.0f);
    wexp[(size_t)t * HW_ + hw] = expf(-k * a);
  }
}

// ---------------------------------------------------------------------------
// K_prep_w: lwT[j][c] = bf16(lin_w[c][j]), owT[j][c] = bf16(out_w[c][j])
// ---------------------------------------------------------------------------
__global__ __launch_bounds__(256) void k_prep_w(const float* __restrict__ lw,
                                                const float* __restrict__ ow,
                                                unsigned short* __restrict__ lwT,
                                                unsigned short* __restrict__ owT) {
  int i = blockIdx.x * 256 + threadIdx.x;
  if (i < 384 * 192) {
    int j = i / 192, c = i - j * 192;
    lwT[i] = f2bf(lw[c * 384 + j]);
  } else if (i < 384 * 192 + 192 * 192) {
    int k = i - 384 * 192;
    int j = k / 192, c = k - j * 192;
    owT[k] = f2bf(ow[c * 192 + j]);
  }
}

// ---------------------------------------------------------------------------
// K1 (v4): fused depthwise 3x3 conv + bias + transpose-to-bf16, row-reuse.
// 384 thr: thread = (pos-group pg of 4 consecutive positions in one image
// row, channel-group cg of 8). Per channel: 1 aligned float4 + 2 edge
// scalars per row = 9 loads for 4 outputs (2.25/out, half of v2's 9/out).
// Masks fold into weights (rows) and corner values (cols) as exact x1/x0 ->
// bitwise-identical to v2 math.
// ---------------------------------------------------------------------------
__global__ __launch_bounds__(384) void k_convt(const float* __restrict__ x,
                                               const float* __restrict__ dww,
                                               const float* __restrict__ dwb,
                                               unsigned short* __restrict__ yT) {
  __shared__ unsigned short t[64 * 200];
  int b = blockIdx.y, pt = blockIdx.x;
  int tid = threadIdx.x;
  int pg = tid & 15, cg = tid >> 4;   // cg in [0,24)
  int p0 = pg * 4;
  int pos0 = pt * 64 + p0;
  int h = pos0 / 56, w0 = pos0 - h * 56;   // 4-group never crosses a row (56%4==0)
  bool hn = h > 0, hp = h < 55, wn = w0 > 0, wq = w0 < 52;
  int oL = wn ? -1 : 0, oR = wq ? 4 : 3;
  int rN = hn ? -56 : 0, rP = hp ? 56 : 0;
  float mL = wn ? 1.f : 0.f, mR = wq ? 1.f : 0.f;
  float mN = hn ? 1.f : 0.f, mP = hp ? 1.f : 0.f;
  const float* xb = x + (size_t)b * CHW_ + (size_t)h * 56 + w0;
  short8 vv0, vv1, vv2, vv3;
#pragma unroll
  for (int e = 0; e < 8; ++e) {
    int c = cg * 8 + e;
    const float* xc = xb + (size_t)c * HW_;
    const float* xt = xc + rN;
    const float* xq = xc + rP;
    float4 m4 = *(const float4*)xc;
    float lm = xc[oL], rm = xc[oR];
    float4 t4 = *(const float4*)xt;
    float lt = xt[oL], rt = xt[oR];
    float4 b4 = *(const float4*)xq;
    float lbv = xq[oL], rbv = xq[oR];
    const float* w9 = dww + c * 9;
    float w0t = w9[0] * mN, w1t = w9[1] * mN, w2t = w9[2] * mN;
    float w3m = w9[3], w4m = w9[4], w5m = w9[5];
    float w6b = w9[6] * mP, w7b = w9[7] * mP, w8b = w9[8] * mP;
    float bias = dwb[c];
    float rT[6] = {lt * mL, t4.x, t4.y, t4.z, t4.w, rt * mR};
    float rM[6] = {lm * mL, m4.x, m4.y, m4.z, m4.w, rm * mR};
    float rB[6] = {lbv * mL, b4.x, b4.y, b4.z, b4.w, rbv * mR};
    float o4[4];
#pragma unroll
    for (int i = 0; i < 4; ++i) {
      float a = bias;
      a = fmaf(rT[i], w0t, a);
      a = fmaf(rT[i + 1], w1t, a);
      a = fmaf(rT[i + 2], w2t, a);
      a = fmaf(rM[i], w3m, a);
      a = fmaf(rM[i + 1], w4m, a);
      a = fmaf(rM[i + 2], w5m, a);
      a = fmaf(rB[i], w6b, a);
      a = fmaf(rB[i + 1], w7b, a);
      a = fmaf(rB[i + 2], w8b, a);
      o4[i] = a;
    }
    vv0[e] = (short)f2bf(o4[0]);
    vv1[e] = (short)f2bf(o4[1]);
    vv2[e] = (short)f2bf(o4[2]);
    vv3[e] = (short)f2bf(o4[3]);
  }
  int c0 = cg * 8;
  *(short8*)&t[(p0 + 0) * 200 + (c0 ^ swz(p0 + 0))] = vv0;
  *(short8*)&t[(p0 + 1) * 200 + (c0 ^ swz(p0 + 1))] = vv1;
  *(short8*)&t[(p0 + 2) * 200 + (c0 ^ swz(p0 + 2))] = vv2;
  *(short8*)&t[(p0 + 3) * 200 + (c0 ^ swz(p0 + 3))] = vv3;
  __syncthreads();
  unsigned short* og = yT + ((size_t)b * HW_ + pt * 64) * C_;
#pragma unroll
  for (int q = 0; q < 4; ++q) {
    int idx = q * 384 + tid;          // < 1536 = 64 pos x 24 chunks
    int pp = idx / 24, cb = idx - pp * 24;
    short8 v = *(const short8*)&t[pp * 200 + ((cb * 8) ^ swz(pp))];
    *(short8*)&og[(size_t)idx * 8] = v;
  }
}

// ---------------------------------------------------------------------------
// K2: GEMM1 via MFMA bf16.
// ---------------------------------------------------------------------------
__global__ __launch_bounds__(256) void k_gemm1(const unsigned short* __restrict__ yT,
                                               const unsigned short* __restrict__ lwT,
                                               const float* __restrict__ lb,
                                               float* __restrict__ xp,
                                               float* __restrict__ zb) {
  constexpr int LD = 40;
  __shared__ unsigned short sA[128 * LD];
  __shared__ unsigned short sY[128 * LD];
  int b = blockIdx.y;
  int bx = blockIdx.x;
  int xcd = bx & 7, o8 = bx >> 3;
  int lg = (xcd < 3 ? xcd * 10 : 30 + (xcd - 3) * 9) + o8;
  int pt = lg / 3, jt = lg % 3;
  int pos0 = pt * 128, j0 = jt * 128;
  int tid = threadIdx.x, lane = tid & 63, wv = tid >> 6;
  int wm = wv & 1, wn = wv >> 1;

  int row0 = tid >> 2, row1 = 64 + (tid >> 2), cb = (tid & 3) * 8;
  const unsigned short* a0 = lwT + (size_t)(j0 + row0) * C_ + cb;
  const unsigned short* a1 = lwT + (size_t)(j0 + row1) * C_ + cb;
  int pr0 = pos0 + row0; if (pr0 > HW_ - 1) pr0 = HW_ - 1;
  int pr1 = pos0 + row1; if (pr1 > HW_ - 1) pr1 = HW_ - 1;
  const unsigned short* b0 = yT + ((size_t)b * HW_ + pr0) * C_ + cb;
  const unsigned short* b1 = yT + ((size_t)b * HW_ + pr1) * C_ + cb;
  int d0 = row0 * LD + cb, d1 = row1 * LD + cb;

  f32x4 acc[4][4] = {};
  for (int kk = 0; kk < C_; kk += 32) {
    short8 va0 = *(const short8*)(a0 + kk);
    short8 va1 = *(const short8*)(a1 + kk);
    short8 vb0 = *(const short8*)(b0 + kk);
    short8 vb1 = *(const short8*)(b1 + kk);
    if (kk) __syncthreads();
    *(short8*)&sA[d0] = va0;
    *(short8*)&sA[d1] = va1;
    *(short8*)&sY[d0] = vb0;
    *(short8*)&sY[d1] = vb1;
    __syncthreads();
    int ra = (wm * 64 + (lane & 15)) * LD + (lane >> 4) * 8;
    int rb = (wn * 64 + (lane & 15)) * LD + (lane >> 4) * 8;
    short8 af[4], bf[4];
#pragma unroll
    for (int m = 0; m < 4; ++m) af[m] = *(const short8*)&sA[ra + m * 16 * LD];
#pragma unroll
    for (int n = 0; n < 4; ++n) bf[n] = *(const short8*)&sY[rb + n * 16 * LD];
#pragma unroll
    for (int m = 0; m < 4; ++m)
#pragma unroll
      for (int n = 0; n < 4; ++n)
        acc[m][n] = __builtin_amdgcn_mfma_f32_16x16x32_bf16(af[m], bf[n], acc[m][n], 0, 0, 0);
  }

#pragma unroll
  for (int m = 0; m < 4; ++m) {
    int jb = j0 + wm * 64 + m * 16 + (lane >> 4) * 4;
#pragma unroll
    for (int r = 0; r < 4; ++r) {
      int jg = jb + r;
      float bias = lb[jg];
      float* base = (jg < C_) ? (xp + ((size_t)b * C_ + jg) * HW_)
                              : (zb + ((size_t)b * C_ + (jg - C_)) * HW_);
#pragma unroll
      for (int n = 0; n < 4; ++n) {
        int pos = pos0 + wn * 64 + n * 16 + (lane & 15);
        if (pos < HW_) base[pos] = acc[m][n][r] + bias;
      }
    }
  }
}

// ---------------------------------------------------------------------------
// K4 (v2): spectral sandwich via bf16 MFMA, per (b,c) plane, in-place d_out.
// ---------------------------------------------------------------------------
__global__ __launch_bounds__(256) void k_spec(const float* xp,
                                              const float* __restrict__ cos_tab,
                                              const float* __restrict__ wexp,
                                              float* sout) {
  constexpr int LDT = 72;
  __shared__ unsigned short lds[4 * 64 * LDT];
  __shared__ float sW[56 * 57];
  unsigned short* sCn = lds;                 // [n][h] = cos[n][h]
  unsigned short* sCt = lds + 64 * LDT;      // [h][n] = cos[n][h]
  unsigned short* sP  = lds + 2 * 64 * LDT;  // [w][h] = P[h][w]
  unsigned short* sT  = lds + 3 * 64 * LDT;  // intermediate
  const int tid = threadIdx.x;
  const int bc = blockIdx.x;
  const int c = bc % C_;

  {  // zero pad regions (whole bf16 area)
    uint2* z = (uint2*)lds;
    for (int i = tid; i < 4608; i += 256) z[i] = make_uint2(0u, 0u);
  }
  __syncthreads();

  const float* Pp = xp + (size_t)bc * HW_;
  const float* Wp = wexp + (size_t)c * HW_;
  for (int e = tid; e < HW_; e += 256) {
    int n = e / 56, m = e - n * 56;
    unsigned short cv = f2bf(cos_tab[e]);
    sCn[n * LDT + m] = cv;
    sCt[m * LDT + n] = cv;
    sP[m * LDT + n] = f2bf(Pp[e]);
    sW[n * 57 + m] = Wp[e];
  }
  __syncthreads();

  const int lane = tid & 63, wv = tid >> 6;
  const int wm = wv & 1, wn = wv >> 1;
  const int lr = lane & 15, lk = lane >> 4;
  const int rt0 = wm * 2, ct0 = wn * 2;
  short8 af[2][2], bg[2][2];
  f32x4 acc[2][2];

#define LOADFRAGS(Ab, Bb)                                                        \
  {                                                                              \
    _Pragma("unroll") for (int i = 0; i < 2; ++i) {                              \
      _Pragma("unroll") for (int k = 0; k < 2; ++k) {                            \
        af[i][k] = *(const short8*)&Ab[((rt0 + i) * 16 + lr) * LDT + k * 32 + lk * 8]; \
        bg[i][k] = *(const short8*)&Bb[((ct0 + i) * 16 + lr) * LDT + k * 32 + lk * 8]; \
      }                                                                          \
    }                                                                            \
  }
#define DOMFMA()                                                                 \
  {                                                                              \
    _Pragma("unroll") for (int i = 0; i < 2; ++i) {                              \
      _Pragma("unroll") for (int j = 0; j < 2; ++j) {                            \
        acc[i][j] = {};                                                          \
        acc[i][j] = __builtin_amdgcn_mfma_f32_16x16x32_bf16(af[i][0], bg[j][0], acc[i][j], 0, 0, 0); \
        acc[i][j] = __builtin_amdgcn_mfma_f32_16x16x32_bf16(af[i][1], bg[j][1], acc[i][j], 0, 0, 0); \
      }                                                                          \
    }                                                                            \
  }

  // stage 1: D1[n][w] = sum_h Cn[n][h] * P^T[w][h]  -> sT[n][w]
  LOADFRAGS(sCn, sP);
  __syncthreads();
  DOMFMA();
#pragma unroll
  for (int i = 0; i < 2; ++i)
#pragma unroll
    for (int j = 0; j < 2; ++j)
#pragma unroll
      for (int r = 0; r < 4; ++r)
        sT[((rt0 + i) * 16 + lk * 4 + r) * LDT + (ct0 + j) * 16 + lr] = f2bf(acc[i][j][r]);
  __syncthreads();

  // stage 2: D2[n][m] = sum_w T1[n][w] * Cm[m][w]; gate by W; store sT[m][n]
  LOADFRAGS(sT, sCn);
  __syncthreads();
  DOMFMA();
#pragma unroll
  for (int i = 0; i < 2; ++i)
#pragma unroll
    for (int j = 0; j < 2; ++j) {
      int n0 = (rt0 + i) * 16 + lk * 4;
      int m = (ct0 + j) * 16 + lr;
      int mc = m < 56 ? m : 55;
      short4v pk;
#pragma unroll
      for (int r = 0; r < 4; ++r) {
        int n = n0 + r;
        int nc = n < 56 ? n : 55;
        pk[r] = (short)f2bf(acc[i][j][r] * sW[nc * 57 + mc]);
      }
      *(short4v*)&sT[m * LDT + n0] = pk;
    }
  __syncthreads();

  // stage 3: D3[h][m] = sum_n CnT[h][n] * T2T[m][n]  -> sT[h][m]
  LOADFRAGS(sCt, sT);
  __syncthreads();
  DOMFMA();
#pragma unroll
  for (int i = 0; i < 2; ++i)
#pragma unroll
    for (int j = 0; j < 2; ++j)
#pragma unroll
      for (int r = 0; r < 4; ++r)
        sT[((rt0 + i) * 16 + lk * 4 + r) * LDT + (ct0 + j) * 16 + lr] = f2bf(acc[i][j][r]);
  __syncthreads();

  // stage 4: D4[h][w] = sum_m T3[h][m] * CmT[w][m]  -> global S[h][w]
  LOADFRAGS(sT, sCt);
  DOMFMA();
  float* So = sout + (size_t)bc * HW_;
#pragma unroll
  for (int i = 0; i < 2; ++i)
#pragma unroll
    for (int j = 0; j < 2; ++j) {
      int w = (ct0 + j) * 16 + lr;
      if (w < 56) {
#pragma unroll
        for (int r = 0; r < 4; ++r) {
          int h = (rt0 + i) * 16 + lk * 4 + r;
          if (h < 56) So[h * 56 + w] = acc[i][j][r];
        }
      }
    }
#undef LOADFRAGS
#undef DOMFMA
}

// ---------------------------------------------------------------------------
// K5: LayerNorm -> silu-gate -> GEMM2 via MFMA bf16.
// ---------------------------------------------------------------------------
__global__ __launch_bounds__(256) void k_ln2(const float* s,
                                             const float* __restrict__ z,
                                             const float* __restrict__ gamma,
                                             const float* __restrict__ beta,
                                             const unsigned short* __restrict__ owT,
                                             const float* __restrict__ ob,
                                             float* out) {
  __shared__ unsigned short act[64 * 200];
  __shared__ float red[8][64];
  __shared__ float smu[64], srs[64];
  int b = blockIdx.y, pt = blockIdx.x;
  int tid = threadIdx.x, lane = tid & 63, wv = tid >> 6;
  int p = lane, cr = wv;
  const float* sp = s + (size_t)b * CHW_ + (size_t)(48 * cr) * HW_ + pt * 64 + p;
  const float* zp = z + (size_t)b * CHW_ + (size_t)(48 * cr) * HW_ + pt * 64 + p;
  float sv[48];
  float sum = 0.f, sq = 0.f;
#pragma unroll
  for (int i = 0; i < 48; ++i) {
    float v = sp[(size_t)i * HW_];
    sv[i] = v;
    sum += v;
    sq = fmaf(v, v, sq);
  }
  red[cr][p] = sum;
  red[4 + cr][p] = sq;
  __syncthreads();
  if (tid < 64) {
    float s1 = red[0][tid] + red[1][tid] + red[2][tid] + red[3][tid];
    float s2 = red[4][tid] + red[5][tid] + red[6][tid] + red[7][tid];
    float mu = s1 * (1.0f / 192.0f);
    float var = s2 * (1.0f / 192.0f) - mu * mu;
    smu[tid] = mu;
    srs[tid] = rsqrtf(var + 1e-5f);
  }
  __syncthreads();
  float mu = smu[p], rs = srs[p];
#pragma unroll
  for (int q = 0; q < 6; ++q) {
    short8 vv;
#pragma unroll
    for (int e = 0; e < 8; ++e) {
      int i = 8 * q + e;
      int c = 48 * cr + i;
      float v = (sv[i] - mu) * rs * gamma[c] + beta[c];
      float zz = zp[(size_t)i * HW_];
      v *= zz / (1.0f + expf(-zz));
      vv[e] = (short)f2bf(v);
    }
    *(short8*)&act[p * 200 + ((48 * cr + 8 * q) ^ swz(p))] = vv;
  }
  __syncthreads();

  f32x4 acc[3][4] = {};
  const unsigned short* ap = owT + (size_t)(wv * 48 + (lane & 15)) * C_ + (lane >> 4) * 8;
#pragma unroll
  for (int kk = 0; kk < C_; kk += 32) {
    short8 af[3], bf[4];
#pragma unroll
    for (int m = 0; m < 3; ++m) af[m] = *(const short8*)(ap + m * 16 * C_ + kk);
#pragma unroll
    for (int n = 0; n < 4; ++n) {
      int row = (lane & 15) + 16 * n;
      int co = (kk + (lane >> 4) * 8) ^ swz(row);
      bf[n] = *(const short8*)&act[row * 200 + co];
    }
#pragma unroll
    for (int m = 0; m < 3; ++m)
#pragma unroll
      for (int n = 0; n < 4; ++n)
        acc[m][n] = __builtin_amdgcn_mfma_f32_16x16x32_bf16(af[m], bf[n], acc[m][n], 0, 0, 0);
  }

  float* op = out + (size_t)b * CHW_ + pt * 64;
#pragma unroll
  for (int m = 0; m < 3; ++m) {
    int jb = wv * 48 + m * 16 + (lane >> 4) * 4;
#pragma unroll
    for (int r = 0; r < 4; ++r) {
      int j = jb + r;
      float bias = ob[j];
#pragma unroll
      for (int n = 0; n < 4; ++n) {
        int pos = n * 16 + (lane & 15);
        op[(size_t)j * HW_ + pos] = acc[m][n][r] + bias;
      }
    }
  }
}

}  // namespace

extern "C" void kernel_launch(void* const* d_in, const int* in_sizes, int n_in,
                              void* d_out, int out_size, void* d_ws, size_t ws_size,
                              hipStream_t stream) {
  const float* x = (const float*)d_in[0];
  const float* dww = (const float*)d_in[1];
  const float* dwb = (const float*)d_in[2];
  const float* lw = (const float*)d_in[3];
  const float* lb = (const float*)d_in[4];
  const float* tkw = (const float*)d_in[5];
  const float* tkb = (const float*)d_in[6];
  const float* fe = (const float*)d_in[7];
  const float* gamma = (const float*)d_in[8];
  const float* beta = (const float*)d_in[9];
  const float* ow = (const float*)d_in[10];
  const float* obias = (const float*)d_in[11];
  float* out = (float*)d_out;

  float* ws = (float*)d_ws;
  float* cos_tab = ws;                                  // 3136 f
  float* wexp = cos_tab + HW_;                          // 602112 f
  float* zb = wexp + CHW_;                              // 38535168 f
  unsigned short* lwT = (unsigned short*)(zb + (size_t)B_ * CHW_);  // 73728 u16
  unsigned short* owT = lwT + 384 * C_;                 // 36864 u16
  unsigned short* yT = owT + C_ * C_;                   // 38535168 u16

  hipLaunchKernelGGL(k_tables, dim3(13), dim3(256), 0, stream, cos_tab);
  hipLaunchKernelGGL(k_wexp, dim3(HW_ / 16), dim3(192), 0, stream, fe, tkw, tkb, wexp);
  hipLaunchKernelGGL(k_prep_w, dim3(432), dim3(256), 0, stream, lw, ow, lwT, owT);
  hipLaunchKernelGGL(k_convt, dim3(HW_ / 64, B_), dim3(384), 0, stream, x, dww, dwb, yT);
  hipLaunchKernelGGL(k_gemm1, dim3(75, B_), dim3(256), 0, stream, yT, lwT, lb, out, zb);
  hipLaunchKernelGGL(k_spec, dim3(B_ * C_), dim3(256), 0, stream, out, cos_tab, wexp, out);
  hipLaunchKernelGGL(k_ln2, dim3(HW_ / 64, B_), dim3(256), 0, stream, out, zb, gamma, beta,
                     owT, obias, out);
}

// Round 9
// 528.984 us; speedup vs baseline: 1.3493x; 1.0349x over previous
//
#include <hip/hip_runtime.h>
#include <math.h>

namespace {

constexpr int B_ = 64;
constexpr int C_ = 192;
constexpr int H_ = 56;
constexpr int W_ = 56;
constexpr int HW_ = H_ * W_;          // 3136
constexpr int CHW_ = C_ * HW_;        // 602112
constexpr float PI_F = 3.14159265358979323846f;

typedef __attribute__((ext_vector_type(8))) short short8;
typedef __attribute__((ext_vector_type(4))) short short4v;
typedef __attribute__((ext_vector_type(4))) float f32x4;

__device__ inline unsigned short f2bf(float f) {
  union { float f; unsigned u; } v{f};
  unsigned r = v.u + 0x7FFFu + ((v.u >> 16) & 1u);
  return (unsigned short)(r >> 16);
}

// XOR swizzle for [row][c] bf16 tiles, row stride 200 elems (16B granular)
__device__ inline int swz(int row) { return ((row >> 1) & 7) << 3; }

// ---------------------------------------------------------------------------
// K0: DCT-II basis table
// ---------------------------------------------------------------------------
__global__ void k_tables(float* __restrict__ cos_tab) {
  int i = blockIdx.x * 256 + threadIdx.x;
  if (i >= HW_) return;
  int n = i / W_;
  int x = i - n * W_;
  float wx = ((float)x + 0.5f) / 56.0f;
  float v = cosf(((float)n * wx) * PI_F) * 0.18898223650461362f;
  if (n == 0) v *= 0.7071067811865476f;
  cos_tab[i] = v;
}

// ---------------------------------------------------------------------------
// K_wexp: wexp[c][hw] = exp(-relu(fe@tok_w+tok_b) * (n^2+m^2))
// ---------------------------------------------------------------------------
__global__ __launch_bounds__(192) void k_wexp(const float* __restrict__ fe,
                                              const float* __restrict__ tkw,
                                              const float* __restrict__ tkb,
                                              float* __restrict__ wexp) {
  __shared__ float sfe[16][C_];
  int hw0 = blockIdx.x * 16;
  int t = threadIdx.x;
  for (int p = 0; p < 16; ++p) sfe[p][t] = fe[(size_t)(hw0 + p) * C_ + t];
  __syncthreads();
  float acc[16];
#pragma unroll
  for (int p = 0; p < 16; ++p) acc[p] = 0.f;
  for (int i = 0; i < C_; ++i) {
    float wv = tkw[i * C_ + t];
#pragma unroll
    for (int p = 0; p < 16; ++p) acc[p] = fmaf(sfe[p][i], wv, acc[p]);
  }
  float bias = tkb[t];
  const float step = PI_F / 56.0f;
#pragma unroll
  for (int p = 0; p < 16; ++p) {
    int hw = hw0 + p;
    int hh = hw / W_;
    int ww = hw - hh * W_;
    float nh = step * (float)hh;
    float nm = step * (float)ww;
    float a = nh * nh + nm * nm;
    float k = fmaxf(acc[p] + bias, 0.0f);
    wexp[(size_t)t * HW_ + hw] = expf(-k * a);
  }
}

// ---------------------------------------------------------------------------
// K_prep_w: lwT[j][c] = bf16(lin_w[c][j]), owT[j][c] = bf16(out_w[c][j])
// ---------------------------------------------------------------------------
__global__ __launch_bounds__(256) void k_prep_w(const float* __restrict__ lw,
                                                const float* __restrict__ ow,
                                                unsigned short* __restrict__ lwT,
                                                unsigned short* __restrict__ owT) {
  int i = blockIdx.x * 256 + threadIdx.x;
  if (i < 384 * 192) {
    int j = i / 192, c = i - j * 192;
    lwT[i] = f2bf(lw[c * 384 + j]);
  } else if (i < 384 * 192 + 192 * 192) {
    int k = i - 384 * 192;
    int j = k / 192, c = k - j * 192;
    owT[k] = f2bf(ow[c * 192 + j]);
  }
}

// ---------------------------------------------------------------------------
// K1 (v4): fused depthwise 3x3 conv + bias + transpose-to-bf16, row-reuse.
// ---------------------------------------------------------------------------
__global__ __launch_bounds__(384) void k_convt(const float* __restrict__ x,
                                               const float* __restrict__ dww,
                                               const float* __restrict__ dwb,
                                               unsigned short* __restrict__ yT) {
  __shared__ unsigned short t[64 * 200];
  int b = blockIdx.y, pt = blockIdx.x;
  int tid = threadIdx.x;
  int pg = tid & 15, cg = tid >> 4;   // cg in [0,24)
  int p0 = pg * 4;
  int pos0 = pt * 64 + p0;
  int h = pos0 / 56, w0 = pos0 - h * 56;   // 4-group never crosses a row (56%4==0)
  bool hn = h > 0, hp = h < 55, wn = w0 > 0, wq = w0 < 52;
  int oL = wn ? -1 : 0, oR = wq ? 4 : 3;
  int rN = hn ? -56 : 0, rP = hp ? 56 : 0;
  float mL = wn ? 1.f : 0.f, mR = wq ? 1.f : 0.f;
  float mN = hn ? 1.f : 0.f, mP = hp ? 1.f : 0.f;
  const float* xb = x + (size_t)b * CHW_ + (size_t)h * 56 + w0;
  short8 vv0, vv1, vv2, vv3;
#pragma unroll
  for (int e = 0; e < 8; ++e) {
    int c = cg * 8 + e;
    const float* xc = xb + (size_t)c * HW_;
    const float* xt = xc + rN;
    const float* xq = xc + rP;
    float4 m4 = *(const float4*)xc;
    float lm = xc[oL], rm = xc[oR];
    float4 t4 = *(const float4*)xt;
    float lt = xt[oL], rt = xt[oR];
    float4 b4 = *(const float4*)xq;
    float lbv = xq[oL], rbv = xq[oR];
    const float* w9 = dww + c * 9;
    float w0t = w9[0] * mN, w1t = w9[1] * mN, w2t = w9[2] * mN;
    float w3m = w9[3], w4m = w9[4], w5m = w9[5];
    float w6b = w9[6] * mP, w7b = w9[7] * mP, w8b = w9[8] * mP;
    float bias = dwb[c];
    float rT[6] = {lt * mL, t4.x, t4.y, t4.z, t4.w, rt * mR};
    float rM[6] = {lm * mL, m4.x, m4.y, m4.z, m4.w, rm * mR};
    float rB[6] = {lbv * mL, b4.x, b4.y, b4.z, b4.w, rbv * mR};
    float o4[4];
#pragma unroll
    for (int i = 0; i < 4; ++i) {
      float a = bias;
      a = fmaf(rT[i], w0t, a);
      a = fmaf(rT[i + 1], w1t, a);
      a = fmaf(rT[i + 2], w2t, a);
      a = fmaf(rM[i], w3m, a);
      a = fmaf(rM[i + 1], w4m, a);
      a = fmaf(rM[i + 2], w5m, a);
      a = fmaf(rB[i], w6b, a);
      a = fmaf(rB[i + 1], w7b, a);
      a = fmaf(rB[i + 2], w8b, a);
      o4[i] = a;
    }
    vv0[e] = (short)f2bf(o4[0]);
    vv1[e] = (short)f2bf(o4[1]);
    vv2[e] = (short)f2bf(o4[2]);
    vv3[e] = (short)f2bf(o4[3]);
  }
  int c0 = cg * 8;
  *(short8*)&t[(p0 + 0) * 200 + (c0 ^ swz(p0 + 0))] = vv0;
  *(short8*)&t[(p0 + 1) * 200 + (c0 ^ swz(p0 + 1))] = vv1;
  *(short8*)&t[(p0 + 2) * 200 + (c0 ^ swz(p0 + 2))] = vv2;
  *(short8*)&t[(p0 + 3) * 200 + (c0 ^ swz(p0 + 3))] = vv3;
  __syncthreads();
  unsigned short* og = yT + ((size_t)b * HW_ + pt * 64) * C_;
#pragma unroll
  for (int q = 0; q < 4; ++q) {
    int idx = q * 384 + tid;          // < 1536 = 64 pos x 24 chunks
    int pp = idx / 24, cb = idx - pp * 24;
    short8 v = *(const short8*)&t[pp * 200 + ((cb * 8) ^ swz(pp))];
    *(short8*)&og[(size_t)idx * 8] = v;
  }
}

// ---------------------------------------------------------------------------
// K2: GEMM1 via MFMA bf16.
// ---------------------------------------------------------------------------
__global__ __launch_bounds__(256) void k_gemm1(const unsigned short* __restrict__ yT,
                                               const unsigned short* __restrict__ lwT,
                                               const float* __restrict__ lb,
                                               float* __restrict__ xp,
                                               float* __restrict__ zb) {
  constexpr int LD = 40;
  __shared__ unsigned short sA[128 * LD];
  __shared__ unsigned short sY[128 * LD];
  int b = blockIdx.y;
  int bx = blockIdx.x;
  int xcd = bx & 7, o8 = bx >> 3;
  int lg = (xcd < 3 ? xcd * 10 : 30 + (xcd - 3) * 9) + o8;
  int pt = lg / 3, jt = lg % 3;
  int pos0 = pt * 128, j0 = jt * 128;
  int tid = threadIdx.x, lane = tid & 63, wv = tid >> 6;
  int wm = wv & 1, wn = wv >> 1;

  int row0 = tid >> 2, row1 = 64 + (tid >> 2), cb = (tid & 3) * 8;
  const unsigned short* a0 = lwT + (size_t)(j0 + row0) * C_ + cb;
  const unsigned short* a1 = lwT + (size_t)(j0 + row1) * C_ + cb;
  int pr0 = pos0 + row0; if (pr0 > HW_ - 1) pr0 = HW_ - 1;
  int pr1 = pos0 + row1; if (pr1 > HW_ - 1) pr1 = HW_ - 1;
  const unsigned short* b0 = yT + ((size_t)b * HW_ + pr0) * C_ + cb;
  const unsigned short* b1 = yT + ((size_t)b * HW_ + pr1) * C_ + cb;
  int d0 = row0 * LD + cb, d1 = row1 * LD + cb;

  f32x4 acc[4][4] = {};
  for (int kk = 0; kk < C_; kk += 32) {
    short8 va0 = *(const short8*)(a0 + kk);
    short8 va1 = *(const short8*)(a1 + kk);
    short8 vb0 = *(const short8*)(b0 + kk);
    short8 vb1 = *(const short8*)(b1 + kk);
    if (kk) __syncthreads();
    *(short8*)&sA[d0] = va0;
    *(short8*)&sA[d1] = va1;
    *(short8*)&sY[d0] = vb0;
    *(short8*)&sY[d1] = vb1;
    __syncthreads();
    int ra = (wm * 64 + (lane & 15)) * LD + (lane >> 4) * 8;
    int rb = (wn * 64 + (lane & 15)) * LD + (lane >> 4) * 8;
    short8 af[4], bf[4];
#pragma unroll
    for (int m = 0; m < 4; ++m) af[m] = *(const short8*)&sA[ra + m * 16 * LD];
#pragma unroll
    for (int n = 0; n < 4; ++n) bf[n] = *(const short8*)&sY[rb + n * 16 * LD];
#pragma unroll
    for (int m = 0; m < 4; ++m)
#pragma unroll
      for (int n = 0; n < 4; ++n)
        acc[m][n] = __builtin_amdgcn_mfma_f32_16x16x32_bf16(af[m], bf[n], acc[m][n], 0, 0, 0);
  }

#pragma unroll
  for (int m = 0; m < 4; ++m) {
    int jb = j0 + wm * 64 + m * 16 + (lane >> 4) * 4;
#pragma unroll
    for (int r = 0; r < 4; ++r) {
      int jg = jb + r;
      float bias = lb[jg];
      float* base = (jg < C_) ? (xp + ((size_t)b * C_ + jg) * HW_)
                              : (zb + ((size_t)b * C_ + (jg - C_)) * HW_);
#pragma unroll
      for (int n = 0; n < 4; ++n) {
        int pos = pos0 + wn * 64 + n * 16 + (lane & 15);
        if (pos < HW_) base[pos] = acc[m][n][r] + bias;
      }
    }
  }
}

// ---------------------------------------------------------------------------
// K4 (v3): spectral sandwich via bf16 MFMA, per (b,c) plane, in-place d_out.
// Reordered chain (w-DCT first) so the P plane stages ROW-MAJOR (vectorized):
//   Q[h][m] = sum_w P[h][w]  C[m][w]    (store Q^T packed)
//   R[n][m] = sum_h C[n][h]  Q^T[m][h]  (gate by W, store R'^T packed)
//   U[h][m] = sum_n C^T[h][n] R'^T[m][n](store scatter [h][m])
//   S[h][w] = sum_m U[h][m]  C^T[w][m]  -> global
// Pad-zero only (disjoint from staged data -> zero || stage, 1 barrier saved);
// sT needs no zeroing (fully written by stage 1).
// ---------------------------------------------------------------------------
__global__ __launch_bounds__(256) void k_spec(const float* xp,
                                              const float* __restrict__ cos_tab,
                                              const float* __restrict__ wexp,
                                              float* sout) {
  constexpr int LDT = 72;
  __shared__ unsigned short sC[64 * LDT];   // [n][h] = cos row-major
  __shared__ unsigned short sCt[64 * LDT];  // [h][n] = cos transposed
  __shared__ unsigned short sP[64 * LDT];   // [h][w] = P row-major
  __shared__ unsigned short sT[64 * LDT];   // intermediate
  __shared__ float sW[56 * 57];
  const int tid = threadIdx.x;
  const int bc = blockIdx.x;
  const int c = bc % C_;
  const float* Pp = xp + (size_t)bc * HW_;
  const float* Wp = wexp + (size_t)c * HW_;

  // pad-zero (rows 0-55 cols 56-71; rows 56-63 full) for sC, sCt, sP
  for (int u = tid; u < 1104; u += 256) {
    int bsel = u / 368, r = u - bsel * 368;
    unsigned short* base = bsel == 0 ? sC : (bsel == 1 ? sCt : sP);
    uint2* zp;
    if (r < 224) {
      int row = r >> 2, q = r & 3;
      zp = (uint2*)&base[row * LDT + 56 + q * 4];
    } else {
      int rr = r - 224;
      int row = 56 + rr / 18, q = rr - (rr / 18) * 18;
      zp = (uint2*)&base[row * LDT + q * 4];
    }
    *zp = make_uint2(0u, 0u);
  }
  // vectorized row-major staging: sC (cos) and sP (P)
  for (int u = tid; u < 784; u += 256) {
    int uu = u < 392 ? u : u - 392;
    int n = uu / 7, w0 = (uu - n * 7) * 8;
    const float* src = (u < 392 ? cos_tab : Pp) + n * 56 + w0;
    float4 a = *(const float4*)src;
    float4 b = *(const float4*)(src + 4);
    short8 v;
    v[0] = (short)f2bf(a.x); v[1] = (short)f2bf(a.y);
    v[2] = (short)f2bf(a.z); v[3] = (short)f2bf(a.w);
    v[4] = (short)f2bf(b.x); v[5] = (short)f2bf(b.y);
    v[6] = (short)f2bf(b.z); v[7] = (short)f2bf(b.w);
    *(short8*)&((u < 392 ? sC : sP)[n * LDT + w0]) = v;
  }
  // scalar staging: transposed cos + W gate
  for (int e = tid; e < HW_; e += 256) {
    int n = e / 56, m = e - n * 56;
    sCt[m * LDT + n] = f2bf(cos_tab[e]);
    sW[n * 57 + m] = Wp[e];
  }
  __syncthreads();

  const int lane = tid & 63, wv = tid >> 6;
  const int wm = wv & 1, wn = wv >> 1;
  const int lr = lane & 15, lk = lane >> 4;
  const int rt0 = wm * 2, ct0 = wn * 2;
  short8 af[2][2], bg[2][2];
  f32x4 acc[2][2];

#define LOADFRAGS(Ab, Bb)                                                        \
  {                                                                              \
    _Pragma("unroll") for (int i = 0; i < 2; ++i) {                              \
      _Pragma("unroll") for (int k = 0; k < 2; ++k) {                            \
        af[i][k] = *(const short8*)&Ab[((rt0 + i) * 16 + lr) * LDT + k * 32 + lk * 8]; \
        bg[i][k] = *(const short8*)&Bb[((ct0 + i) * 16 + lr) * LDT + k * 32 + lk * 8]; \
      }                                                                          \
    }                                                                            \
  }
#define DOMFMA()                                                                 \
  {                                                                              \
    _Pragma("unroll") for (int i = 0; i < 2; ++i) {                              \
      _Pragma("unroll") for (int j = 0; j < 2; ++j) {                            \
        acc[i][j] = {};                                                          \
        acc[i][j] = __builtin_amdgcn_mfma_f32_16x16x32_bf16(af[i][0], bg[j][0], acc[i][j], 0, 0, 0); \
        acc[i][j] = __builtin_amdgcn_mfma_f32_16x16x32_bf16(af[i][1], bg[j][1], acc[i][j], 0, 0, 0); \
      }                                                                          \
    }                                                                            \
  }

  // stage 1: Q[h][m] = sum_w sP[h][w]*sC[m][w] -> sT[m][h] packed (no alias)
  LOADFRAGS(sP, sC);
  DOMFMA();
#pragma unroll
  for (int i = 0; i < 2; ++i)
#pragma unroll
    for (int j = 0; j < 2; ++j) {
      int h0 = (rt0 + i) * 16 + lk * 4;
      int m = (ct0 + j) * 16 + lr;
      short4v pk;
#pragma unroll
      for (int r = 0; r < 4; ++r) pk[r] = (short)f2bf(acc[i][j][r]);
      *(short4v*)&sT[m * LDT + h0] = pk;
    }
  __syncthreads();

  // stage 2: R[n][m] = sum_h sC[n][h]*sT[m][h]; gate W[n][m]; -> sT[m][n] packed
  LOADFRAGS(sC, sT);
  __syncthreads();
  DOMFMA();
#pragma unroll
  for (int i = 0; i < 2; ++i)
#pragma unroll
    for (int j = 0; j < 2; ++j) {
      int n0 = (rt0 + i) * 16 + lk * 4;
      int m = (ct0 + j) * 16 + lr;
      int mc = m < 56 ? m : 55;
      short4v pk;
#pragma unroll
      for (int r = 0; r < 4; ++r) {
        int n = n0 + r;
        int nc = n < 56 ? n : 55;
        pk[r] = (short)f2bf(acc[i][j][r] * sW[nc * 57 + mc]);
      }
      *(short4v*)&sT[m * LDT + n0] = pk;
    }
  __syncthreads();

  // stage 3: U[h][m] = sum_n sCt[h][n]*sT[m][n] -> sT[h][m] scatter
  LOADFRAGS(sCt, sT);
  __syncthreads();
  DOMFMA();
#pragma unroll
  for (int i = 0; i < 2; ++i)
#pragma unroll
    for (int j = 0; j < 2; ++j)
#pragma unroll
      for (int r = 0; r < 4; ++r)
        sT[((rt0 + i) * 16 + lk * 4 + r) * LDT + (ct0 + j) * 16 + lr] = f2bf(acc[i][j][r]);
  __syncthreads();

  // stage 4: S[h][w] = sum_m sT[h][m]*sCt[w][m] -> global
  LOADFRAGS(sT, sCt);
  DOMFMA();
  float* So = sout + (size_t)bc * HW_;
#pragma unroll
  for (int i = 0; i < 2; ++i)
#pragma unroll
    for (int j = 0; j < 2; ++j) {
      int w = (ct0 + j) * 16 + lr;
      if (w < 56) {
#pragma unroll
        for (int r = 0; r < 4; ++r) {
          int h = (rt0 + i) * 16 + lk * 4 + r;
          if (h < 56) So[h * 56 + w] = acc[i][j][r];
        }
      }
    }
#undef LOADFRAGS
#undef DOMFMA
}

// ---------------------------------------------------------------------------
// K5: LayerNorm -> silu-gate -> GEMM2 via MFMA bf16.
// ---------------------------------------------------------------------------
__global__ __launch_bounds__(256) void k_ln2(const float* s,
                                             const float* __restrict__ z,
                                             const float* __restrict__ gamma,
                                             const float* __restrict__ beta,
                                             const unsigned short* __restrict__ owT,
                                             const float* __restrict__ ob,
                                             float* out) {
  __shared__ unsigned short act[64 * 200];
  __shared__ float red[8][64];
  __shared__ float smu[64], srs[64];
  int b = blockIdx.y, pt = blockIdx.x;
  int tid = threadIdx.x, lane = tid & 63, wv = tid >> 6;
  int p = lane, cr = wv;
  const float* sp = s + (size_t)b * CHW_ + (size_t)(48 * cr) * HW_ + pt * 64 + p;
  const float* zp = z + (size_t)b * CHW_ + (size_t)(48 * cr) * HW_ + pt * 64 + p;
  float sv[48];
  float sum = 0.f, sq = 0.f;
#pragma unroll
  for (int i = 0; i < 48; ++i) {
    float v = sp[(size_t)i * HW_];
    sv[i] = v;
    sum += v;
    sq = fmaf(v, v, sq);
  }
  red[cr][p] = sum;
  red[4 + cr][p] = sq;
  __syncthreads();
  if (tid < 64) {
    float s1 = red[0][tid] + red[1][tid] + red[2][tid] + red[3][tid];
    float s2 = red[4][tid] + red[5][tid] + red[6][tid] + red[7][tid];
    float mu = s1 * (1.0f / 192.0f);
    float var = s2 * (1.0f / 192.0f) - mu * mu;
    smu[tid] = mu;
    srs[tid] = rsqrtf(var + 1e-5f);
  }
  __syncthreads();
  float mu = smu[p], rs = srs[p];
#pragma unroll
  for (int q = 0; q < 6; ++q) {
    short8 vv;
#pragma unroll
    for (int e = 0; e < 8; ++e) {
      int i = 8 * q + e;
      int c = 48 * cr + i;
      float v = (sv[i] - mu) * rs * gamma[c] + beta[c];
      float zz = zp[(size_t)i * HW_];
      v *= zz / (1.0f + expf(-zz));
      vv[e] = (short)f2bf(v);
    }
    *(short8*)&act[p * 200 + ((48 * cr + 8 * q) ^ swz(p))] = vv;
  }
  __syncthreads();

  f32x4 acc[3][4] = {};
  const unsigned short* ap = owT + (size_t)(wv * 48 + (lane & 15)) * C_ + (lane >> 4) * 8;
#pragma unroll
  for (int kk = 0; kk < C_; kk += 32) {
    short8 af[3], bf[4];
#pragma unroll
    for (int m = 0; m < 3; ++m) af[m] = *(const short8*)(ap + m * 16 * C_ + kk);
#pragma unroll
    for (int n = 0; n < 4; ++n) {
      int row = (lane & 15) + 16 * n;
      int co = (kk + (lane >> 4) * 8) ^ swz(row);
      bf[n] = *(const short8*)&act[row * 200 + co];
    }
#pragma unroll
    for (int m = 0; m < 3; ++m)
#pragma unroll
      for (int n = 0; n < 4; ++n)
        acc[m][n] = __builtin_amdgcn_mfma_f32_16x16x32_bf16(af[m], bf[n], acc[m][n], 0, 0, 0);
  }

  float* op = out + (size_t)b * CHW_ + pt * 64;
#pragma unroll
  for (int m = 0; m < 3; ++m) {
    int jb = wv * 48 + m * 16 + (lane >> 4) * 4;
#pragma unroll
    for (int r = 0; r < 4; ++r) {
      int j = jb + r;
      float bias = ob[j];
#pragma unroll
      for (int n = 0; n < 4; ++n) {
        int pos = n * 16 + (lane & 15);
        op[(size_t)j * HW_ + pos] = acc[m][n][r] + bias;
      }
    }
  }
}

}  // namespace

extern "C" void kernel_launch(void* const* d_in, const int* in_sizes, int n_in,
                              void* d_out, int out_size, void* d_ws, size_t ws_size,
                              hipStream_t stream) {
  const float* x = (const float*)d_in[0];
  const float* dww = (const float*)d_in[1];
  const float* dwb = (const float*)d_in[2];
  const float* lw = (const float*)d_in[3];
  const float* lb = (const float*)d_in[4];
  const float* tkw = (const float*)d_in[5];
  const float* tkb = (const float*)d_in[6];
  const float* fe = (const float*)d_in[7];
  const float* gamma = (const float*)d_in[8];
  const float* beta = (const float*)d_in[9];
  const float* ow = (const float*)d_in[10];
  const float* obias = (const float*)d_in[11];
  float* out = (float*)d_out;

  float* ws = (float*)d_ws;
  float* cos_tab = ws;                                  // 3136 f
  float* wexp = cos_tab + HW_;                          // 602112 f
  float* zb = wexp + CHW_;                              // 38535168 f
  unsigned short* lwT = (unsigned short*)(zb + (size_t)B_ * CHW_);  // 73728 u16
  unsigned short* owT = lwT + 384 * C_;                 // 36864 u16
  unsigned short* yT = owT + C_ * C_;                   // 38535168 u16

  hipLaunchKernelGGL(k_tables, dim3(13), dim3(256), 0, stream, cos_tab);
  hipLaunchKernelGGL(k_wexp, dim3(HW_ / 16), dim3(192), 0, stream, fe, tkw, tkb, wexp);
  hipLaunchKernelGGL(k_prep_w, dim3(432), dim3(256), 0, stream, lw, ow, lwT, owT);
  hipLaunchKernelGGL(k_convt, dim3(HW_ / 64, B_), dim3(384), 0, stream, x, dww, dwb, yT);
  hipLaunchKernelGGL(k_gemm1, dim3(75, B_), dim3(256), 0, stream, yT, lwT, lb, out, zb);
  hipLaunchKernelGGL(k_spec, dim3(B_ * C_), dim3(256), 0, stream, out, cos_tab, wexp, out);
  hipLaunchKernelGGL(k_ln2, dim3(HW_ / 64, B_), dim3(256), 0, stream, out, zb, gamma, beta,
                     owT, obias, out);
}